// Round 12
// baseline (582.483 us; speedup 1.0000x reference)
//
#include <hip/hip_runtime.h>
#include <math.h>

#define NEG_SLOPE 0.2f
#define BN_EPS 1e-5f

template <int N> struct IC { static constexpr int v = N; };

typedef _Float16 half2v __attribute__((ext_vector_type(2)));
typedef _Float16 f16x8 __attribute__((ext_vector_type(8)));
typedef float f32x4v __attribute__((ext_vector_type(4)));

__device__ __forceinline__ half2v u2h(unsigned u) {
  union { unsigned u; half2v h; } c;
  c.u = u;
  return c.h;
}
__device__ __forceinline__ unsigned pkh(float lo, float hi) {
  union { half2v h; unsigned u; } c;
  c.h[0] = (_Float16)lo;
  c.h[1] = (_Float16)hi;
  return c.u;
}

#if defined(__has_builtin)
#if __has_builtin(__builtin_amdgcn_fdot2)
#define FDOT2(a, b, c) __builtin_amdgcn_fdot2((a), (b), (c), false)
#endif
#endif
#ifndef FDOT2
__device__ __forceinline__ float fdot2_sw(half2v a, half2v b, float c) {
  return c + (float)a[0] * (float)b[0] + (float)a[1] * (float)b[1];
}
#define FDOT2(a, b, c) fdot2_sw((a), (b), (c))
#endif

// Fast exp: raw v_exp_f32 (2^x) with att pre-scaled by log2(e).
#if defined(__has_builtin)
#if __has_builtin(__builtin_amdgcn_exp2f)
#define FEXP(x) __builtin_amdgcn_exp2f(x)
#define ATT_SCALE 1.44269504088896f
#endif
#endif
#ifndef FEXP
#define FEXP(x) __expf(x)
#define ATT_SCALE 1.0f
#endif

// FMA of one float4 pair into scalar accumulator (expanded inline at use).
#define FMA4(acc, v, wq) \
  acc += (v).x * (wq).x + (v).y * (wq).y + (v).z * (wq).z + (v).w * (wq).w

// One 64-dot row-pass against register-resident W[16] (float4).
// sched_barrier(0) fences the scheduler (round-4 proven; no spills).
#define DOT_ROW(buf, stride, r, bias, OUT)                                  \
  {                                                                         \
    __builtin_amdgcn_sched_barrier(0);                                      \
    float a0 = 0.f, a1 = 0.f, a2 = 0.f, a3 = 0.f;                           \
    _Pragma("unroll") for (int q = 0; q < 4; q++) {                         \
      float4 v0 = *(const float4*)((buf) + (r) * (stride) + q * 16 + 0);    \
      float4 v1 = *(const float4*)((buf) + (r) * (stride) + q * 16 + 4);    \
      float4 v2 = *(const float4*)((buf) + (r) * (stride) + q * 16 + 8);    \
      float4 v3 = *(const float4*)((buf) + (r) * (stride) + q * 16 + 12);   \
      FMA4(a0, v0, W[q * 4 + 0]);                                           \
      FMA4(a1, v1, W[q * 4 + 1]);                                           \
      FMA4(a2, v2, W[q * 4 + 2]);                                           \
      FMA4(a3, v3, W[q * 4 + 3]);                                           \
    }                                                                       \
    OUT = (bias) + ((a0 + a1) + (a2 + a3));                                 \
  }

// ---------------------------------------------------------------------------
// Per-32-lane-group sum, broadcast to the whole group: 4 DPP row_ror adds
// (row-of-16 sums) + row_bcast15 (lane31/63 hold group totals) + ds_swizzle
// broadcast of lane31 within each 32-group (offset 0x3E0: and=0,or=31,xor=0).
// ---------------------------------------------------------------------------
__device__ __forceinline__ float half_sum32(float v) {
  int x;
  x = __builtin_amdgcn_update_dpp(0, __float_as_int(v), 0x121, 0xF, 0xF, true);
  v += __int_as_float(x);  // row_ror:1
  x = __builtin_amdgcn_update_dpp(0, __float_as_int(v), 0x122, 0xF, 0xF, true);
  v += __int_as_float(x);  // row_ror:2
  x = __builtin_amdgcn_update_dpp(0, __float_as_int(v), 0x124, 0xF, 0xF, true);
  v += __int_as_float(x);  // row_ror:4
  x = __builtin_amdgcn_update_dpp(0, __float_as_int(v), 0x128, 0xF, 0xF, true);
  v += __int_as_float(x);  // row_ror:8 -> row-of-16 sums
  x = __builtin_amdgcn_update_dpp(0, __float_as_int(v), 0x142, 0xF, 0xF, true);
  v += __int_as_float(x);  // row_bcast15: lanes16-31 / 48-63 = group totals
  return __int_as_float(
      __builtin_amdgcn_ds_swizzle(__float_as_int(v), 0x03E0));
}

#if defined(__has_builtin)
#if __has_builtin(__builtin_amdgcn_mfma_f32_16x16x32_f16)
#define HAVE_MFMA16 1
#endif
#endif

// ---------------------------------------------------------------------------
// hist + graph-counts + fp16 weight pack (all independent, one launch).
// ---------------------------------------------------------------------------
__global__ __launch_bounds__(256) void hist_kernel(
    const int* __restrict__ dst, const int* __restrict__ batch,
    int* __restrict__ deg, float* __restrict__ counts,
    const float* __restrict__ Wl, const float* __restrict__ Wr,
    _Float16* __restrict__ w16, int E_, int N_) {
  int i = blockIdx.x * 256 + threadIdx.x;
  if (i < E_) atomicAdd(&deg[dst[i]], 1);
  if (i < N_) atomicAdd(&counts[batch[i]], 1.0f);
  if (i < 24576)
    w16[i] = (i < 12288) ? (_Float16)Wl[i] : (_Float16)Wr[i - 12288];
}

// ---------------------------------------------------------------------------
// scanA: per-256-segment local prefix + totals; FUSED degree histogram
// (128 bins, DESCENDING degree, LDS-aggregated).
// ---------------------------------------------------------------------------
__global__ __launch_bounds__(256) void scanA_kernel(
    const int* __restrict__ deg, int* __restrict__ row_ptr,
    int* __restrict__ segTot, int* __restrict__ bins, int N_, int nseg) {
  __shared__ int sb[256];
  __shared__ int lb[128];
  int t = threadIdx.x;
  if (t < 128) lb[t] = 0;
  __syncthreads();
  for (int s = blockIdx.x; s < nseg; s += gridDim.x) {
    int i = s * 256 + t;
    int v = (i < N_) ? deg[i] : 0;
    if (i < N_) atomicAdd(&lb[127 - min(v, 127)], 1);
    sb[t] = v;
    __syncthreads();
    for (int off = 1; off < 256; off <<= 1) {
      int a = (t >= off) ? sb[t - off] : 0;
      __syncthreads();
      sb[t] += a;
      __syncthreads();
    }
    int incl = sb[t];
    if (i < N_) row_ptr[i] = incl - v;
    if (t == 255) segTot[s] = incl;
    __syncthreads();
  }
  if (t < 128 && lb[t]) atomicAdd(&bins[t], lb[t]);
}

// ---------------------------------------------------------------------------
// scanB: scan segTot; FUSED exclusive scan of the 128 degree bins.
// ---------------------------------------------------------------------------
__global__ __launch_bounds__(256) void scanB_kernel(int* __restrict__ segTot,
                                                    int* __restrict__ bins,
                                                    int nseg) {
  __shared__ int sb[256];
  __shared__ int baseSh;
  int t = threadIdx.x;
  if (t == 0) baseSh = 0;
  __syncthreads();
  for (int c0 = 0; c0 < nseg; c0 += 256) {
    int s = c0 + t;
    int v = (s < nseg) ? segTot[s] : 0;
    sb[t] = v;
    __syncthreads();
    for (int off = 1; off < 256; off <<= 1) {
      int a = (t >= off) ? sb[t - off] : 0;
      __syncthreads();
      sb[t] += a;
      __syncthreads();
    }
    int incl = sb[t];
    int base = baseSh;
    if (s < nseg) segTot[s] = base + incl - v;
    __syncthreads();
    if (t == 255) baseSh = base + incl;
    __syncthreads();
  }
  int v2 = (t < 128) ? bins[t] : 0;
  sb[t] = v2;
  __syncthreads();
  for (int off = 1; off < 256; off <<= 1) {
    int a = (t >= off) ? sb[t - off] : 0;
    __syncthreads();
    sb[t] += a;
    __syncthreads();
  }
  if (t < 128) bins[t] = sb[t] - v2;
}

// ---------------------------------------------------------------------------
// scanC: finalize row_ptr/cursor; FUSED degree-sort scatter; zero csr pads
// (gat's clamped tail reads may touch csr_src[E] when a row is empty).
// ---------------------------------------------------------------------------
__global__ __launch_bounds__(256) void scanC_kernel(
    int* __restrict__ row_ptr, const int* __restrict__ segTot,
    int* __restrict__ cursor, const int* __restrict__ deg,
    int* __restrict__ bins, int* __restrict__ perm,
    int* __restrict__ csr_src, int* __restrict__ csr_eid, int N_, int E_) {
  __shared__ int lb[128];
  __shared__ int lbase[128];
  int t = threadIdx.x;
  if (t < 128) lb[t] = 0;
  __syncthreads();
  int i = blockIdx.x * 256 + t;
  int bin = 0, rk = 0;
  bool ok = (i < N_);
  if (ok) {
    int rp = row_ptr[i] + segTot[i >> 8];
    row_ptr[i] = rp;
    cursor[i] = rp;
    int dg = deg[i];
    bin = 127 - min(dg, 127);
    rk = atomicAdd(&lb[bin], 1);
  }
  if (i == 0) row_ptr[N_] = E_;
  if (blockIdx.x == 0 && t < 16) {
    csr_src[E_ + t] = 0;
    csr_eid[E_ + t] = 0;
  }
  __syncthreads();
  if (t < 128) {
    int c = lb[t];
    lbase[t] = c ? atomicAdd(&bins[t], c) : 0;
  }
  __syncthreads();
  if (ok) perm[lbase[bin] + rk] = i;
}

// ---------------------------------------------------------------------------
// Scatter: 4B-only random writes (L2-resident).
// ---------------------------------------------------------------------------
__global__ __launch_bounds__(256) void scatter_kernel(
    const int* __restrict__ src, const int* __restrict__ dst,
    int* __restrict__ cursor, int* __restrict__ csr_src,
    int* __restrict__ csr_eid, int E_) {
  int e = blockIdx.x * 256 + threadIdx.x;
  if (e >= E_) return;
  int pos = atomicAdd(&cursor[dst[e]], 1);
  csr_src[pos] = src[e];
  csr_eid[pos] = e;
}

// ---------------------------------------------------------------------------
// Permute+convert attr: sequential coalesced 32B writes; random 64B-line
// gathers (each line read exactly once).
// ---------------------------------------------------------------------------
__global__ __launch_bounds__(256) void permute_attr_kernel(
    const float4* __restrict__ edge_attr4, const int* __restrict__ csr_eid,
    unsigned* __restrict__ attr_u, int E_) {
  int p = blockIdx.x * 256 + threadIdx.x;
  if (p >= E_) return;
  int e = csr_eid[p];
  float4 a0 = edge_attr4[(size_t)e * 4 + 0];
  float4 a1 = edge_attr4[(size_t)e * 4 + 1];
  float4 a2 = edge_attr4[(size_t)e * 4 + 2];
  float4 a3 = edge_attr4[(size_t)e * 4 + 3];
  uint4 u0, u1;
  u0.x = pkh(a0.x, a0.y);
  u0.y = pkh(a0.z, a0.w);
  u0.z = pkh(a1.x, a1.y);
  u0.w = pkh(a1.z, a1.w);
  u1.x = pkh(a2.x, a2.y);
  u1.y = pkh(a2.z, a2.w);
  u1.z = pkh(a3.x, a3.y);
  u1.w = pkh(a3.z, a3.w);
  uint4* d4 = (uint4*)(attr_u + (size_t)p * 8);
  d4[0] = u0;
  d4[1] = u1;
}

// ---------------------------------------------------------------------------
// emb + FUSED layer-0 linx (round-11 proven).
// ---------------------------------------------------------------------------
__global__ __launch_bounds__(256, 3) void emb_kernel(
    const float* __restrict__ x, const float* __restrict__ emb_W,
    const float* __restrict__ emb_b, const _Float16* __restrict__ Wl16,
    const float* __restrict__ bl, const _Float16* __restrict__ Wr16,
    const float* __restrict__ br, float* __restrict__ h,
    _Float16* __restrict__ xl, _Float16* __restrict__ xr, int rows) {
  __shared__ float sx[4096];
  __shared__ float sh[64 * 68];
  int lane = threadIdx.x & 63;
  int w = threadIdx.x >> 6;
  int n0 = blockIdx.x * 64;

  {
    int gmax = rows * 64 - 4;
#pragma unroll
    for (int i = 0; i < 4; i++) {
      int off = w * 1024 + i * 256 + lane * 4;
      int g = min(n0 * 64 + off, gmax);
      *(float4*)(sx + off) = *(const float4*)(x + g);
    }
  }

  {
    float4 W[16];
#pragma unroll
    for (int q = 0; q < 16; q++) W[q] = ((const float4*)(emb_W + lane * 64))[q];
    float b = emb_b[lane];
#pragma unroll 1
    for (int t = 0; t < 16; t++) {
      int r = w * 16 + t;
      float a;
      DOT_ROW(sx, 64, r, b, a);
      sh[r * 68 + lane] = a;
      int n = n0 + r;
      if (n < rows) h[(size_t)n * 64 + lane] = a;
    }
  }

#ifdef HAVE_MFMA16
  {
    int r = lane & 15;
    int kg = lane >> 4;
    int nb = n0 + w * 16;
    const float* p = sh + (w * 16 + r) * 68 + kg * 8;
    f16x8 A0, A1;
    {
      float4 xa = *(const float4*)(p);
      float4 xb = *(const float4*)(p + 4);
      A0[0] = (_Float16)xa.x; A0[1] = (_Float16)xa.y;
      A0[2] = (_Float16)xa.z; A0[3] = (_Float16)xa.w;
      A0[4] = (_Float16)xb.x; A0[5] = (_Float16)xb.y;
      A0[6] = (_Float16)xb.z; A0[7] = (_Float16)xb.w;
      xa = *(const float4*)(p + 32);
      xb = *(const float4*)(p + 36);
      A1[0] = (_Float16)xa.x; A1[1] = (_Float16)xa.y;
      A1[2] = (_Float16)xa.z; A1[3] = (_Float16)xa.w;
      A1[4] = (_Float16)xb.x; A1[5] = (_Float16)xb.y;
      A1[6] = (_Float16)xb.z; A1[7] = (_Float16)xb.w;
    }
#pragma unroll
    for (int c = 0; c < 4; c++) {
      int o = c * 16 + r;
      {
        const f16x8* b0 = (const f16x8*)(Wl16 + (size_t)o * 64 + kg * 8);
        const f16x8* b1 = (const f16x8*)(Wl16 + (size_t)o * 64 + 32 + kg * 8);
        f32x4v acc;
        float bv = bl[o];
        acc[0] = bv; acc[1] = bv; acc[2] = bv; acc[3] = bv;
        acc = __builtin_amdgcn_mfma_f32_16x16x32_f16(A0, b0[0], acc, 0, 0, 0);
        acc = __builtin_amdgcn_mfma_f32_16x16x32_f16(A1, b1[0], acc, 0, 0, 0);
#pragma unroll
        for (int g = 0; g < 4; g++) {
          int nd = nb + kg * 4 + g;
          if (nd < rows) xl[(size_t)nd * 64 + o] = (_Float16)acc[g];
        }
      }
      {
        const f16x8* b0 = (const f16x8*)(Wr16 + (size_t)o * 64 + kg * 8);
        const f16x8* b1 = (const f16x8*)(Wr16 + (size_t)o * 64 + 32 + kg * 8);
        f32x4v acc;
        float bv = br[o];
        acc[0] = bv; acc[1] = bv; acc[2] = bv; acc[3] = bv;
        acc = __builtin_amdgcn_mfma_f32_16x16x32_f16(A0, b0[0], acc, 0, 0, 0);
        acc = __builtin_amdgcn_mfma_f32_16x16x32_f16(A1, b1[0], acc, 0, 0, 0);
#pragma unroll
        for (int g = 0; g < 4; g++) {
          int nd = nb + kg * 4 + g;
          if (nd < rows) xr[(size_t)nd * 64 + o] = (_Float16)acc[g];
        }
      }
    }
  }
#endif
}

// ---------------------------------------------------------------------------
// linx via MFMA (round-8 proven). Layers 1,2.
// ---------------------------------------------------------------------------
__global__ __launch_bounds__(256) void linx_mfma_kernel(
    const float* __restrict__ in, const _Float16* __restrict__ Wl16,
    const float* __restrict__ bl, const _Float16* __restrict__ Wr16,
    const float* __restrict__ br, _Float16* __restrict__ xl,
    _Float16* __restrict__ xr, int rows) {
#ifdef HAVE_MFMA16
  int lane = threadIdx.x & 63;
  int w = threadIdx.x >> 6;
  int n0 = blockIdx.x * 64 + w * 16;
  int r = lane & 15;
  int kg = lane >> 4;

  int nA = min(n0 + r, rows - 1);
  f16x8 A0, A1;
  {
    const float* p = in + (size_t)nA * 64 + kg * 8;
    float4 xa = *(const float4*)(p);
    float4 xb = *(const float4*)(p + 4);
    A0[0] = (_Float16)xa.x; A0[1] = (_Float16)xa.y;
    A0[2] = (_Float16)xa.z; A0[3] = (_Float16)xa.w;
    A0[4] = (_Float16)xb.x; A0[5] = (_Float16)xb.y;
    A0[6] = (_Float16)xb.z; A0[7] = (_Float16)xb.w;
    xa = *(const float4*)(p + 32);
    xb = *(const float4*)(p + 36);
    A1[0] = (_Float16)xa.x; A1[1] = (_Float16)xa.y;
    A1[2] = (_Float16)xa.z; A1[3] = (_Float16)xa.w;
    A1[4] = (_Float16)xb.x; A1[5] = (_Float16)xb.y;
    A1[6] = (_Float16)xb.z; A1[7] = (_Float16)xb.w;
  }

#pragma unroll
  for (int c = 0; c < 4; c++) {
    int o = c * 16 + r;
    {
      const f16x8* b0 = (const f16x8*)(Wl16 + (size_t)o * 64 + kg * 8);
      const f16x8* b1 = (const f16x8*)(Wl16 + (size_t)o * 64 + 32 + kg * 8);
      f32x4v acc;
      float bv = bl[o];
      acc[0] = bv; acc[1] = bv; acc[2] = bv; acc[3] = bv;
      acc = __builtin_amdgcn_mfma_f32_16x16x32_f16(A0, b0[0], acc, 0, 0, 0);
      acc = __builtin_amdgcn_mfma_f32_16x16x32_f16(A1, b1[0], acc, 0, 0, 0);
#pragma unroll
      for (int g = 0; g < 4; g++) {
        int nd = n0 + kg * 4 + g;
        if (nd < rows) xl[(size_t)nd * 64 + o] = (_Float16)acc[g];
      }
    }
    {
      const f16x8* b0 = (const f16x8*)(Wr16 + (size_t)o * 64 + kg * 8);
      const f16x8* b1 = (const f16x8*)(Wr16 + (size_t)o * 64 + 32 + kg * 8);
      f32x4v acc;
      float bv = br[o];
      acc[0] = bv; acc[1] = bv; acc[2] = bv; acc[3] = bv;
      acc = __builtin_amdgcn_mfma_f32_16x16x32_f16(A0, b0[0], acc, 0, 0, 0);
      acc = __builtin_amdgcn_mfma_f32_16x16x32_f16(A1, b1[0], acc, 0, 0, 0);
#pragma unroll
      for (int g = 0; g < 4; g++) {
        int nd = n0 + kg * 4 + g;
        if (nd < rows) xr[(size_t)nd * 64 + o] = (_Float16)acc[g];
      }
    }
  }
#endif
}

// ---------------------------------------------------------------------------
// Fused GATv2 layer, 2 nodes per wave: lane covers j = 2jj, 2jj+1 (jj =
// lane&31); halves (lanes 0-31 / 32-63) own different degree-sorted nodes
// (equal-degree pairing from the counting sort). Per-half 32-lane DPP
// reduction + ds_swizzle broadcast; all chunks clamp+masked against the
// half's own degree; NaN-guarded online-max softmax (raw v_exp_f32, exp2
// domain). Epilogue = folded conv_bias+BN, exact GELU, residual (float2).
// ---------------------------------------------------------------------------
template <bool CONTIG>
__global__ __launch_bounds__(256) void gat_fused_kernel(
    const int* __restrict__ perm, const int* __restrict__ csr_src,
    const int* __restrict__ csr_eid, const int* __restrict__ row_ptr,
    const unsigned* __restrict__ attr_u, const float* __restrict__ edge_attr,
    const _Float16* __restrict__ xl, const _Float16* __restrict__ xr,
    const float* __restrict__ We, const float* __restrict__ att,
    const float* __restrict__ conv_bias, const float* __restrict__ gamma,
    const float* __restrict__ beta, const float* __restrict__ mean,
    const float* __restrict__ var, float* __restrict__ h, int N_) {
  int lane = threadIdx.x & 63;
  int jj = lane & 31;
  int nidx = (blockIdx.x * 256 + threadIdx.x) >> 5;  // node slot per half
  int nc = min(nidx, N_ - 1);
  bool alive = (nidx < N_);
  int d = perm[nc];

  // Per-lane (j0=2jj, j1=2jj+1) parameters.
  half2v WekA[8], WekB[8];
  float WekfA[16], WekfB[16];
  if constexpr (CONTIG) {
    const float4* wp = (const float4*)(We + jj * 32);
    float4 w0 = wp[0], w1 = wp[1], w2 = wp[2], w3 = wp[3];
    float4 w4 = wp[4], w5 = wp[5], w6 = wp[6], w7 = wp[7];
    WekA[0][0] = (_Float16)w0.x; WekA[0][1] = (_Float16)w0.y;
    WekA[1][0] = (_Float16)w0.z; WekA[1][1] = (_Float16)w0.w;
    WekA[2][0] = (_Float16)w1.x; WekA[2][1] = (_Float16)w1.y;
    WekA[3][0] = (_Float16)w1.z; WekA[3][1] = (_Float16)w1.w;
    WekA[4][0] = (_Float16)w2.x; WekA[4][1] = (_Float16)w2.y;
    WekA[5][0] = (_Float16)w2.z; WekA[5][1] = (_Float16)w2.w;
    WekA[6][0] = (_Float16)w3.x; WekA[6][1] = (_Float16)w3.y;
    WekA[7][0] = (_Float16)w3.z; WekA[7][1] = (_Float16)w3.w;
    WekB[0][0] = (_Float16)w4.x; WekB[0][1] = (_Float16)w4.y;
    WekB[1][0] = (_Float16)w4.z; WekB[1][1] = (_Float16)w4.w;
    WekB[2][0] = (_Float16)w5.x; WekB[2][1] = (_Float16)w5.y;
    WekB[3][0] = (_Float16)w5.z; WekB[3][1] = (_Float16)w5.w;
    WekB[4][0] = (_Float16)w6.x; WekB[4][1] = (_Float16)w6.y;
    WekB[5][0] = (_Float16)w6.z; WekB[5][1] = (_Float16)w6.w;
    WekB[6][0] = (_Float16)w7.x; WekB[6][1] = (_Float16)w7.y;
    WekB[7][0] = (_Float16)w7.z; WekB[7][1] = (_Float16)w7.w;
  } else {
#pragma unroll
    for (int k = 0; k < 16; k++) WekfA[k] = We[jj * 32 + k];
#pragma unroll
    for (int k = 0; k < 16; k++) WekfB[k] = We[jj * 32 + 16 + k];
  }
  float2 attv = *(const float2*)(att + jj * 2);
  float att0 = attv.x * ATT_SCALE, att1 = attv.y * ATT_SCALE;
  float2 varv = *(const float2*)(var + jj * 2);
  float2 gamv = *(const float2*)(gamma + jj * 2);
  float2 cbv = *(const float2*)(conv_bias + jj * 2);
  float2 mev = *(const float2*)(mean + jj * 2);
  float2 bev = *(const float2*)(beta + jj * 2);
  float sc0 = rsqrtf(varv.x + BN_EPS) * gamv.x;
  float sh0 = (cbv.x - mev.x) * sc0 + bev.x;
  float sc1 = rsqrtf(varv.y + BN_EPS) * gamv.y;
  float sh1 = (cbv.y - mev.y) * sc1 + bev.y;

  int beg = row_ptr[d];
  int end = row_ptr[d + 1];
  int deg = alive ? (end - beg) : 0;
  int degm1 = max(deg - 1, 0);
  int degA = __builtin_amdgcn_readfirstlane(deg);
  int degB = __builtin_amdgcn_readlane(deg, 32);
  int maxdeg = max(degA, degB);

  float xrj0, xrj1;
  {
    unsigned pk = ((const unsigned*)xr)[(size_t)d * 32 + jj];
    half2v hv = u2h(pk);
    xrj0 = (float)hv[0];
    xrj1 = (float)hv[1];
  }

  float m = -INFINITY, l = 0.f, acc0 = 0.f, acc1 = 0.f;

  auto chunk = [&](int base, auto C_) {
    constexpr int C = decltype(C_)::v;
    int idxv[C];
#pragma unroll
    for (int t = 0; t < C; t++) idxv[t] = beg + min(base + t, degm1);
    int si[C];
#pragma unroll
    for (int t = 0; t < C; t++) si[t] = csr_src[idxv[t]];
    unsigned xpk[C];
#pragma unroll
    for (int t = 0; t < C; t++)
      xpk[t] = *(const unsigned*)((const char*)xl + (size_t)si[t] * 128 +
                                  jj * 4);
    float v[C];
#pragma unroll
    for (int t = 0; t < C; t++) {
      float ea0, ea1;
      if constexpr (CONTIG) {
        const uint4* ap = (const uint4*)(attr_u + (size_t)idxv[t] * 8);
        uint4 ua = ap[0], ub = ap[1];
        ea0 = 0.f;
        ea0 = FDOT2(u2h(ua.x), WekA[0], ea0);
        ea0 = FDOT2(u2h(ua.y), WekA[1], ea0);
        ea0 = FDOT2(u2h(ua.z), WekA[2], ea0);
        ea0 = FDOT2(u2h(ua.w), WekA[3], ea0);
        ea0 = FDOT2(u2h(ub.x), WekA[4], ea0);
        ea0 = FDOT2(u2h(ub.y), WekA[5], ea0);
        ea0 = FDOT2(u2h(ub.z), WekA[6], ea0);
        ea0 = FDOT2(u2h(ub.w), WekA[7], ea0);
        ea1 = 0.f;
        ea1 = FDOT2(u2h(ua.x), WekB[0], ea1);
        ea1 = FDOT2(u2h(ua.y), WekB[1], ea1);
        ea1 = FDOT2(u2h(ua.z), WekB[2], ea1);
        ea1 = FDOT2(u2h(ua.w), WekB[3], ea1);
        ea1 = FDOT2(u2h(ub.x), WekB[4], ea1);
        ea1 = FDOT2(u2h(ub.y), WekB[5], ea1);
        ea1 = FDOT2(u2h(ub.z), WekB[6], ea1);
        ea1 = FDOT2(u2h(ub.w), WekB[7], ea1);
      } else {
        int e = csr_eid[idxv[t]];
        const float4* ap = (const float4*)(edge_attr + (size_t)e * 16);
        float4 a0 = ap[0], a1 = ap[1], a2 = ap[2], a3 = ap[3];
        ea0 = a0.x * WekfA[0]  + a0.y * WekfA[1]  + a0.z * WekfA[2]  + a0.w * WekfA[3]
            + a1.x * WekfA[4]  + a1.y * WekfA[5]  + a1.z * WekfA[6]  + a1.w * WekfA[7]
            + a2.x * WekfA[8]  + a2.y * WekfA[9]  + a2.z * WekfA[10] + a2.w * WekfA[11]
            + a3.x * WekfA[12] + a3.y * WekfA[13] + a3.z * WekfA[14] + a3.w * WekfA[15];
        ea1 = a0.x * WekfB[0]  + a0.y * WekfB[1]  + a0.z * WekfB[2]  + a0.w * WekfB[3]
            + a1.x * WekfB[4]  + a1.y * WekfB[5]  + a1.z * WekfB[6]  + a1.w * WekfB[7]
            + a2.x * WekfB[8]  + a2.y * WekfB[9]  + a2.z * WekfB[10] + a2.w * WekfB[11]
            + a3.x * WekfB[12] + a3.y * WekfB[13] + a3.z * WekfB[14] + a3.w * WekfB[15];
      }
      half2v hv = u2h(xpk[t]);
      float z0 = (float)hv[0] + xrj0 + ea0;
      z0 = fmaxf(z0, NEG_SLOPE * z0);
      float z1 = (float)hv[1] + xrj1 + ea1;
      z1 = fmaxf(z1, NEG_SLOPE * z1);
      float p = half_sum32(z0 * att0 + z1 * att1);
      v[t] = (base + t < deg) ? p : -INFINITY;
    }
    float mc = v[0];
#pragma unroll
    for (int t = 1; t < C; t++) mc = fmaxf(mc, v[t]);
    float newm = fmaxf(m, mc);
    float nm2 = (newm < -1e37f) ? 0.f : newm;  // NaN guard: all-masked chunk
    float s = FEXP(m - nm2);                   // m=-inf -> 0
    l *= s;
    acc0 *= s;
    acc1 *= s;
#pragma unroll
    for (int t = 0; t < C; t++) {
      float w = FEXP(v[t] - nm2);  // masked slots: exp(-inf)=0
      l += w;
      half2v hv = u2h(xpk[t]);
      acc0 += w * (float)hv[0];
      acc1 += w * (float)hv[1];
    }
    m = newm;
  };

  int base = 0;
  for (; base + 16 <= maxdeg; base += 16) chunk(base, IC<16>{});
  if (base + 8 <= maxdeg) {
    chunk(base, IC<8>{});
    base += 8;
  }
  if (base + 4 <= maxdeg) {
    chunk(base, IC<4>{});
    base += 4;
  }
  if (base < maxdeg) chunk(base, IC<4>{});

  if (alive) {
    float val0 = acc0 / (l + 1e-16f) * sc0 + sh0;
    float val1 = acc1 / (l + 1e-16f) * sc1 + sh1;
    float g0 = 0.5f * val0 * (1.f + erff(val0 * 0.70710678118654752f));
    float g1 = 0.5f * val1 * (1.f + erff(val1 * 0.70710678118654752f));
    float2* hp = (float2*)(h + (size_t)d * 64 + jj * 2);
    float2 o = *hp;
    o.x += g0;
    o.y += g1;
    *hp = o;
  }
}

// ---------------------------------------------------------------------------
// Final: out128 = h @ lin_W.T + lin_b, pooled per graph (round-4 proven).
// ---------------------------------------------------------------------------
__global__ __launch_bounds__(256, 2) void lin_pool_kernel(
    const float* __restrict__ h, const float* __restrict__ lin_W,
    const float* __restrict__ lin_b, const int* __restrict__ batch,
    const float* __restrict__ counts, float* __restrict__ pooled, int rows) {
  __shared__ float shh[4096];
  int lane = threadIdx.x & 63;
  int w = threadIdx.x >> 6;
  int n0 = blockIdx.x * 64;

  {
    int gmax = rows * 64 - 4;
#pragma unroll
    for (int i = 0; i < 4; i++) {
      int off = w * 1024 + i * 256 + lane * 4;
      int g = min(n0 * 64 + off, gmax);
      *(float4*)(shh + off) = *(const float4*)(h + g);
    }
  }

  float4 W0[16], W1[16];
#pragma unroll
  for (int q = 0; q < 16; q++) W0[q] = ((const float4*)(lin_W + lane * 64))[q];
#pragma unroll
  for (int q = 0; q < 16; q++)
    W1[q] = ((const float4*)(lin_W + (lane + 64) * 64))[q];
  float b0 = lin_b[lane], b1 = lin_b[lane + 64];

  int curg = -1;
  float acc0 = 0.f, acc1 = 0.f;
  int lim = min(16, rows - n0 - w * 16);
#pragma unroll 1
  for (int t = 0; t < lim; t++) {
    int r = w * 16 + t;
    __builtin_amdgcn_sched_barrier(0);
    float d0 = b0, d1 = b1;
#pragma unroll
    for (int q = 0; q < 16; q++) {
      float4 v = *(const float4*)(shh + r * 64 + q * 4);
      FMA4(d0, v, W0[q]);
      FMA4(d1, v, W1[q]);
    }
    int g = batch[n0 + r];
    if (g != curg) {
      if (curg >= 0) {
        float inv = 1.f / fmaxf(counts[curg], 1.f);
        atomicAdd(&pooled[curg * 128 + lane], acc0 * inv);
        atomicAdd(&pooled[curg * 128 + 64 + lane], acc1 * inv);
      }
      curg = g;
      acc0 = 0.f;
      acc1 = 0.f;
    }
    acc0 += d0;
    acc1 += d1;
  }
  if (curg >= 0) {
    float inv = 1.f / fmaxf(counts[curg], 1.f);
    atomicAdd(&pooled[curg * 128 + lane], acc0 * inv);
    atomicAdd(&pooled[curg * 128 + 64 + lane], acc1 * inv);
  }
}

extern "C" void kernel_launch(void* const* d_in, const int* in_sizes, int n_in,
                              void* d_out, int out_size, void* d_ws, size_t ws_size,
                              hipStream_t stream) {
  const float* x         = (const float*)d_in[0];
  const int*   edge_index= (const int*)  d_in[1];
  const float* edge_attr = (const float*)d_in[2];
  const int*   batch     = (const int*)  d_in[3];
  const float* emb_W     = (const float*)d_in[4];
  const float* emb_b     = (const float*)d_in[5];
  const float* Wl        = (const float*)d_in[6];
  const float* bl        = (const float*)d_in[7];
  const float* Wr        = (const float*)d_in[8];
  const float* br        = (const float*)d_in[9];
  const float* We        = (const float*)d_in[10];
  const float* att       = (const float*)d_in[11];
  const float* conv_bias = (const float*)d_in[12];
  const float* bn_gamma  = (const float*)d_in[13];
  const float* bn_beta   = (const float*)d_in[14];
  const float* bn_mean   = (const float*)d_in[15];
  const float* bn_var    = (const float*)d_in[16];
  const float* lin_W     = (const float*)d_in[17];
  const float* lin_b     = (const float*)d_in[18];

  const int N_ = in_sizes[0] / 64;
  const int E_ = in_sizes[1] / 2;
  const int G_ = out_size / 128;
  const int* src = edge_index;
  const int* dst = edge_index + E_;

  const int Npad = (N_ + 3) & ~3;
  const int Epad = (E_ + 19) & ~3;
  const int nseg = (N_ + 255) / 256;

  // Workspace layout (floats). xl/xr fp16. w16 = fp16 Wl(3)+Wr(3) packed.
  float* ws      = (float*)d_ws;
  float* h       = ws;                                 // N*64
  _Float16* xl   = (_Float16*)(h + (size_t)N_ * 64);   // N*64 halfs
  _Float16* xr   = xl + (size_t)N_ * 64;               // N*64 halfs
  int*   csr_src = (int*)(xr + (size_t)N_ * 64);       // Epad
  int*   csr_eid = csr_src + Epad;                     // Epad
  int*   row_ptr = csr_eid + Epad;                     // Npad+4
  int*   cursor  = row_ptr + (Npad + 4);               // Npad
  int*   deg     = cursor + Npad;                      // Npad
  float* counts  = (float*)(deg + Npad);               // G
  int*   segTot  = (int*)(counts + G_);                // nseg+8
  int*   bins    = segTot + nseg + 8;                  // 128
  int*   perm    = bins + 128;                         // Npad
  uintptr_t abp  = (uintptr_t)(perm + Npad);
  abp = (abp + 15) & ~(uintptr_t)15;
  _Float16* w16  = (_Float16*)abp;                     // 24576 halfs (48KB)
  uintptr_t abp2 = abp + 24576 * sizeof(_Float16);
  unsigned* attr_u = (unsigned*)abp2;                  // E*8 uints (optional)

  size_t base_bytes = (abp2 - (uintptr_t)d_ws);
  bool contig = ws_size >= base_bytes + (size_t)E_ * 32 + 64;

  const int hgrid = (max(E_, N_) + 255) / 256;
  const int ngrid = (N_ + 255) / 256;
  const int egrid = (E_ + 255) / 256;

  // --- CSR build + counts + degree-sort + weight pack (fused chain) ---
  hipMemsetAsync(deg, 0, ((size_t)Npad + G_ + nseg + 8 + 128) * 4, stream);
  hist_kernel<<<hgrid, 256, 0, stream>>>(dst, batch, deg, counts, Wl, Wr,
                                         w16, E_, N_);
  scanA_kernel<<<min(nseg, 1024), 256, 0, stream>>>(deg, row_ptr, segTot,
                                                    bins, N_, nseg);
  scanB_kernel<<<1, 256, 0, stream>>>(segTot, bins, nseg);
  scanC_kernel<<<ngrid, 256, 0, stream>>>(row_ptr, segTot, cursor, deg, bins,
                                          perm, csr_src, csr_eid, N_, E_);
  scatter_kernel<<<egrid, 256, 0, stream>>>(src, dst, cursor, csr_src,
                                            csr_eid, E_);
  if (contig) {
    permute_attr_kernel<<<egrid, 256, 0, stream>>>(
        (const float4*)edge_attr, csr_eid, attr_u, E_);
  }

  // emb (fp32-exact) + fused layer-0 xl/xr (MFMA from LDS slab)
  const int tgrid = (N_ + 63) / 64;
  emb_kernel<<<tgrid, 256, 0, stream>>>(x, emb_W, emb_b, w16, bl,
                                        w16 + 12288, br, h, xl, xr, N_);

  const int gatBlocks = (N_ + 7) / 8;  // 2 nodes per wave, 8 per block
  for (int l = 0; l < 3; l++) {
    if (l > 0) {
      linx_mfma_kernel<<<tgrid, 256, 0, stream>>>(
          h, w16 + (size_t)l * 4096, bl + l * 64,
          w16 + 12288 + (size_t)l * 4096, br + l * 64, xl, xr, N_);
    }
    if (contig) {
      gat_fused_kernel<true><<<gatBlocks, 256, 0, stream>>>(
          perm, csr_src, csr_eid, row_ptr, attr_u, edge_attr, xl, xr,
          We + (size_t)l * 1024, att + l * 64, conv_bias + l * 64,
          bn_gamma + l * 64, bn_beta + l * 64, bn_mean + l * 64,
          bn_var + l * 64, h, N_);
    } else {
      gat_fused_kernel<false><<<gatBlocks, 256, 0, stream>>>(
          perm, csr_src, csr_eid, row_ptr, attr_u, edge_attr, xl, xr,
          We + (size_t)l * 1024, att + l * 64, conv_bias + l * 64,
          bn_gamma + l * 64, bn_beta + l * 64, bn_mean + l * 64,
          bn_var + l * 64, h, N_);
    }
  }

  hipMemsetAsync(d_out, 0, (size_t)G_ * 128 * 4, stream);
  lin_pool_kernel<<<(N_ + 63) / 64, 256, 0, stream>>>(
      h, lin_W, lin_b, batch, counts, (float*)d_out, N_);
}

// Round 13
// 546.587 us; speedup vs baseline: 1.0657x; 1.0657x over previous
//
#include <hip/hip_runtime.h>
#include <math.h>

#define NEG_SLOPE 0.2f
#define BN_EPS 1e-5f

template <int N> struct IC { static constexpr int v = N; };
template <bool B> struct BC { static constexpr bool v = B; };

typedef _Float16 half2v __attribute__((ext_vector_type(2)));
typedef _Float16 f16x8 __attribute__((ext_vector_type(8)));
typedef float f32x4v __attribute__((ext_vector_type(4)));

__device__ __forceinline__ half2v u2h(unsigned u) {
  union { unsigned u; half2v h; } c;
  c.u = u;
  return c.h;
}
__device__ __forceinline__ unsigned pkh(float lo, float hi) {
  union { half2v h; unsigned u; } c;
  c.h[0] = (_Float16)lo;
  c.h[1] = (_Float16)hi;
  return c.u;
}

#if defined(__has_builtin)
#if __has_builtin(__builtin_amdgcn_fdot2)
#define FDOT2(a, b, c) __builtin_amdgcn_fdot2((a), (b), (c), false)
#endif
#endif
#ifndef FDOT2
__device__ __forceinline__ float fdot2_sw(half2v a, half2v b, float c) {
  return c + (float)a[0] * (float)b[0] + (float)a[1] * (float)b[1];
}
#define FDOT2(a, b, c) fdot2_sw((a), (b), (c))
#endif

// Fast exp: raw v_exp_f32 (2^x) with att pre-scaled by log2(e).
#if defined(__has_builtin)
#if __has_builtin(__builtin_amdgcn_exp2f)
#define FEXP(x) __builtin_amdgcn_exp2f(x)
#define ATT_SCALE 1.44269504088896f
#endif
#endif
#ifndef FEXP
#define FEXP(x) __expf(x)
#define ATT_SCALE 1.0f
#endif

// FMA of one float4 pair into scalar accumulator (expanded inline at use).
#define FMA4(acc, v, wq) \
  acc += (v).x * (wq).x + (v).y * (wq).y + (v).z * (wq).z + (v).w * (wq).w

// One 64-dot row-pass against register-resident W[16] (float4).
// sched_barrier(0) fences the scheduler (round-4 proven; no spills).
#define DOT_ROW(buf, stride, r, bias, OUT)                                  \
  {                                                                         \
    __builtin_amdgcn_sched_barrier(0);                                      \
    float a0 = 0.f, a1 = 0.f, a2 = 0.f, a3 = 0.f;                           \
    _Pragma("unroll") for (int q = 0; q < 4; q++) {                         \
      float4 v0 = *(const float4*)((buf) + (r) * (stride) + q * 16 + 0);    \
      float4 v1 = *(const float4*)((buf) + (r) * (stride) + q * 16 + 4);    \
      float4 v2 = *(const float4*)((buf) + (r) * (stride) + q * 16 + 8);    \
      float4 v3 = *(const float4*)((buf) + (r) * (stride) + q * 16 + 12);   \
      FMA4(a0, v0, W[q * 4 + 0]);                                           \
      FMA4(a1, v1, W[q * 4 + 1]);                                           \
      FMA4(a2, v2, W[q * 4 + 2]);                                           \
      FMA4(a3, v3, W[q * 4 + 3]);                                           \
    }                                                                       \
    OUT = (bias) + ((a0 + a1) + (a2 + a3));                                 \
  }

// ---------------------------------------------------------------------------
// VALU-only 64-lane sum, zero LDS ops (round-6 proven).
// ---------------------------------------------------------------------------
__device__ __forceinline__ float wave_sum64(float v) {
  int x;
  x = __builtin_amdgcn_update_dpp(0, __float_as_int(v), 0x121, 0xF, 0xF, true);
  v += __int_as_float(x);  // row_ror:1
  x = __builtin_amdgcn_update_dpp(0, __float_as_int(v), 0x122, 0xF, 0xF, true);
  v += __int_as_float(x);  // row_ror:2
  x = __builtin_amdgcn_update_dpp(0, __float_as_int(v), 0x124, 0xF, 0xF, true);
  v += __int_as_float(x);  // row_ror:4
  x = __builtin_amdgcn_update_dpp(0, __float_as_int(v), 0x128, 0xF, 0xF, true);
  v += __int_as_float(x);  // row_ror:8
  x = __builtin_amdgcn_update_dpp(0, __float_as_int(v), 0x142, 0xF, 0xF, true);
  v += __int_as_float(x);  // row_bcast15
  x = __builtin_amdgcn_update_dpp(0, __float_as_int(v), 0x143, 0xF, 0xF, true);
  v += __int_as_float(x);  // row_bcast31: lanes48-63 = total
  return __int_as_float(__builtin_amdgcn_readlane(__float_as_int(v), 63));
}

#if defined(__has_builtin)
#if __has_builtin(__builtin_amdgcn_mfma_f32_16x16x32_f16)
#define HAVE_MFMA16 1
#endif
#endif

// ---------------------------------------------------------------------------
// hist + graph-counts + fp16 weight pack (all independent, one launch).
// ---------------------------------------------------------------------------
__global__ __launch_bounds__(256) void hist_kernel(
    const int* __restrict__ dst, const int* __restrict__ batch,
    int* __restrict__ deg, float* __restrict__ counts,
    const float* __restrict__ Wl, const float* __restrict__ Wr,
    _Float16* __restrict__ w16, int E_, int N_) {
  int i = blockIdx.x * 256 + threadIdx.x;
  if (i < E_) atomicAdd(&deg[dst[i]], 1);
  if (i < N_) atomicAdd(&counts[batch[i]], 1.0f);
  if (i < 24576)
    w16[i] = (i < 12288) ? (_Float16)Wl[i] : (_Float16)Wr[i - 12288];
}

// ---------------------------------------------------------------------------
// scanA: per-256-segment local prefix + totals; FUSED degree histogram
// (128 bins, DESCENDING degree, LDS-aggregated).
// ---------------------------------------------------------------------------
__global__ __launch_bounds__(256) void scanA_kernel(
    const int* __restrict__ deg, int* __restrict__ row_ptr,
    int* __restrict__ segTot, int* __restrict__ bins, int N_, int nseg) {
  __shared__ int sb[256];
  __shared__ int lb[128];
  int t = threadIdx.x;
  if (t < 128) lb[t] = 0;
  __syncthreads();
  for (int s = blockIdx.x; s < nseg; s += gridDim.x) {
    int i = s * 256 + t;
    int v = (i < N_) ? deg[i] : 0;
    if (i < N_) atomicAdd(&lb[127 - min(v, 127)], 1);
    sb[t] = v;
    __syncthreads();
    for (int off = 1; off < 256; off <<= 1) {
      int a = (t >= off) ? sb[t - off] : 0;
      __syncthreads();
      sb[t] += a;
      __syncthreads();
    }
    int incl = sb[t];
    if (i < N_) row_ptr[i] = incl - v;
    if (t == 255) segTot[s] = incl;
    __syncthreads();
  }
  if (t < 128 && lb[t]) atomicAdd(&bins[t], lb[t]);
}

// ---------------------------------------------------------------------------
// scanB: scan segTot; FUSED exclusive scan of the 128 degree bins.
// ---------------------------------------------------------------------------
__global__ __launch_bounds__(256) void scanB_kernel(int* __restrict__ segTot,
                                                    int* __restrict__ bins,
                                                    int nseg) {
  __shared__ int sb[256];
  __shared__ int baseSh;
  int t = threadIdx.x;
  if (t == 0) baseSh = 0;
  __syncthreads();
  for (int c0 = 0; c0 < nseg; c0 += 256) {
    int s = c0 + t;
    int v = (s < nseg) ? segTot[s] : 0;
    sb[t] = v;
    __syncthreads();
    for (int off = 1; off < 256; off <<= 1) {
      int a = (t >= off) ? sb[t - off] : 0;
      __syncthreads();
      sb[t] += a;
      __syncthreads();
    }
    int incl = sb[t];
    int base = baseSh;
    if (s < nseg) segTot[s] = base + incl - v;
    __syncthreads();
    if (t == 255) baseSh = base + incl;
    __syncthreads();
  }
  int v2 = (t < 128) ? bins[t] : 0;
  sb[t] = v2;
  __syncthreads();
  for (int off = 1; off < 256; off <<= 1) {
    int a = (t >= off) ? sb[t - off] : 0;
    __syncthreads();
    sb[t] += a;
    __syncthreads();
  }
  if (t < 128) bins[t] = sb[t] - v2;
}

// ---------------------------------------------------------------------------
// scanC: finalize row_ptr/cursor; FUSED degree-sort scatter; zero csr pads.
// ---------------------------------------------------------------------------
__global__ __launch_bounds__(256) void scanC_kernel(
    int* __restrict__ row_ptr, const int* __restrict__ segTot,
    int* __restrict__ cursor, const int* __restrict__ deg,
    int* __restrict__ bins, int* __restrict__ perm,
    int* __restrict__ csr_src, int* __restrict__ csr_eid, int N_, int E_) {
  __shared__ int lb[128];
  __shared__ int lbase[128];
  int t = threadIdx.x;
  if (t < 128) lb[t] = 0;
  __syncthreads();
  int i = blockIdx.x * 256 + t;
  int bin = 0, rk = 0;
  bool ok = (i < N_);
  if (ok) {
    int rp = row_ptr[i] + segTot[i >> 8];
    row_ptr[i] = rp;
    cursor[i] = rp;
    int dg = deg[i];
    bin = 127 - min(dg, 127);
    rk = atomicAdd(&lb[bin], 1);
  }
  if (i == 0) row_ptr[N_] = E_;
  if (blockIdx.x == 0 && t < 16) {
    csr_src[E_ + t] = 0;
    csr_eid[E_ + t] = 0;
  }
  __syncthreads();
  if (t < 128) {
    int c = lb[t];
    lbase[t] = c ? atomicAdd(&bins[t], c) : 0;
  }
  __syncthreads();
  if (ok) perm[lbase[bin] + rk] = i;
}

// ---------------------------------------------------------------------------
// Scatter: 4B-only random writes (L2-resident).
// ---------------------------------------------------------------------------
__global__ __launch_bounds__(256) void scatter_kernel(
    const int* __restrict__ src, const int* __restrict__ dst,
    int* __restrict__ cursor, int* __restrict__ csr_src,
    int* __restrict__ csr_eid, int E_) {
  int e = blockIdx.x * 256 + threadIdx.x;
  if (e >= E_) return;
  int pos = atomicAdd(&cursor[dst[e]], 1);
  csr_src[pos] = src[e];
  csr_eid[pos] = e;
}

// ---------------------------------------------------------------------------
// Permute+convert attr: sequential coalesced 32B writes; random 64B-line
// gathers (each line read exactly once).
// ---------------------------------------------------------------------------
__global__ __launch_bounds__(256) void permute_attr_kernel(
    const float4* __restrict__ edge_attr4, const int* __restrict__ csr_eid,
    unsigned* __restrict__ attr_u, int E_) {
  int p = blockIdx.x * 256 + threadIdx.x;
  if (p >= E_) return;
  int e = csr_eid[p];
  float4 a0 = edge_attr4[(size_t)e * 4 + 0];
  float4 a1 = edge_attr4[(size_t)e * 4 + 1];
  float4 a2 = edge_attr4[(size_t)e * 4 + 2];
  float4 a3 = edge_attr4[(size_t)e * 4 + 3];
  uint4 u0, u1;
  u0.x = pkh(a0.x, a0.y);
  u0.y = pkh(a0.z, a0.w);
  u0.z = pkh(a1.x, a1.y);
  u0.w = pkh(a1.z, a1.w);
  u1.x = pkh(a2.x, a2.y);
  u1.y = pkh(a2.z, a2.w);
  u1.z = pkh(a3.x, a3.y);
  u1.w = pkh(a3.z, a3.w);
  uint4* d4 = (uint4*)(attr_u + (size_t)p * 8);
  d4[0] = u0;
  d4[1] = u1;
}

// ---------------------------------------------------------------------------
// emb + FUSED layer-0 linx (round-11 proven).
// ---------------------------------------------------------------------------
__global__ __launch_bounds__(256, 3) void emb_kernel(
    const float* __restrict__ x, const float* __restrict__ emb_W,
    const float* __restrict__ emb_b, const _Float16* __restrict__ Wl16,
    const float* __restrict__ bl, const _Float16* __restrict__ Wr16,
    const float* __restrict__ br, float* __restrict__ h,
    _Float16* __restrict__ xl, _Float16* __restrict__ xr, int rows) {
  __shared__ float sx[4096];
  __shared__ float sh[64 * 68];
  int lane = threadIdx.x & 63;
  int w = threadIdx.x >> 6;
  int n0 = blockIdx.x * 64;

  {
    int gmax = rows * 64 - 4;
#pragma unroll
    for (int i = 0; i < 4; i++) {
      int off = w * 1024 + i * 256 + lane * 4;
      int g = min(n0 * 64 + off, gmax);
      *(float4*)(sx + off) = *(const float4*)(x + g);
    }
  }

  {
    float4 W[16];
#pragma unroll
    for (int q = 0; q < 16; q++) W[q] = ((const float4*)(emb_W + lane * 64))[q];
    float b = emb_b[lane];
#pragma unroll 1
    for (int t = 0; t < 16; t++) {
      int r = w * 16 + t;
      float a;
      DOT_ROW(sx, 64, r, b, a);
      sh[r * 68 + lane] = a;
      int n = n0 + r;
      if (n < rows) h[(size_t)n * 64 + lane] = a;
    }
  }

#ifdef HAVE_MFMA16
  {
    int r = lane & 15;
    int kg = lane >> 4;
    int nb = n0 + w * 16;
    const float* p = sh + (w * 16 + r) * 68 + kg * 8;
    f16x8 A0, A1;
    {
      float4 xa = *(const float4*)(p);
      float4 xb = *(const float4*)(p + 4);
      A0[0] = (_Float16)xa.x; A0[1] = (_Float16)xa.y;
      A0[2] = (_Float16)xa.z; A0[3] = (_Float16)xa.w;
      A0[4] = (_Float16)xb.x; A0[5] = (_Float16)xb.y;
      A0[6] = (_Float16)xb.z; A0[7] = (_Float16)xb.w;
      xa = *(const float4*)(p + 32);
      xb = *(const float4*)(p + 36);
      A1[0] = (_Float16)xa.x; A1[1] = (_Float16)xa.y;
      A1[2] = (_Float16)xa.z; A1[3] = (_Float16)xa.w;
      A1[4] = (_Float16)xb.x; A1[5] = (_Float16)xb.y;
      A1[6] = (_Float16)xb.z; A1[7] = (_Float16)xb.w;
    }
#pragma unroll
    for (int c = 0; c < 4; c++) {
      int o = c * 16 + r;
      {
        const f16x8* b0 = (const f16x8*)(Wl16 + (size_t)o * 64 + kg * 8);
        const f16x8* b1 = (const f16x8*)(Wl16 + (size_t)o * 64 + 32 + kg * 8);
        f32x4v acc;
        float bv = bl[o];
        acc[0] = bv; acc[1] = bv; acc[2] = bv; acc[3] = bv;
        acc = __builtin_amdgcn_mfma_f32_16x16x32_f16(A0, b0[0], acc, 0, 0, 0);
        acc = __builtin_amdgcn_mfma_f32_16x16x32_f16(A1, b1[0], acc, 0, 0, 0);
#pragma unroll
        for (int g = 0; g < 4; g++) {
          int nd = nb + kg * 4 + g;
          if (nd < rows) xl[(size_t)nd * 64 + o] = (_Float16)acc[g];
        }
      }
      {
        const f16x8* b0 = (const f16x8*)(Wr16 + (size_t)o * 64 + kg * 8);
        const f16x8* b1 = (const f16x8*)(Wr16 + (size_t)o * 64 + 32 + kg * 8);
        f32x4v acc;
        float bv = br[o];
        acc[0] = bv; acc[1] = bv; acc[2] = bv; acc[3] = bv;
        acc = __builtin_amdgcn_mfma_f32_16x16x32_f16(A0, b0[0], acc, 0, 0, 0);
        acc = __builtin_amdgcn_mfma_f32_16x16x32_f16(A1, b1[0], acc, 0, 0, 0);
#pragma unroll
        for (int g = 0; g < 4; g++) {
          int nd = nb + kg * 4 + g;
          if (nd < rows) xr[(size_t)nd * 64 + o] = (_Float16)acc[g];
        }
      }
    }
  }
#endif
}

// ---------------------------------------------------------------------------
// linx via MFMA (round-8 proven). Layers 1,2.
// ---------------------------------------------------------------------------
__global__ __launch_bounds__(256) void linx_mfma_kernel(
    const float* __restrict__ in, const _Float16* __restrict__ Wl16,
    const float* __restrict__ bl, const _Float16* __restrict__ Wr16,
    const float* __restrict__ br, _Float16* __restrict__ xl,
    _Float16* __restrict__ xr, int rows) {
#ifdef HAVE_MFMA16
  int lane = threadIdx.x & 63;
  int w = threadIdx.x >> 6;
  int n0 = blockIdx.x * 64 + w * 16;
  int r = lane & 15;
  int kg = lane >> 4;

  int nA = min(n0 + r, rows - 1);
  f16x8 A0, A1;
  {
    const float* p = in + (size_t)nA * 64 + kg * 8;
    float4 xa = *(const float4*)(p);
    float4 xb = *(const float4*)(p + 4);
    A0[0] = (_Float16)xa.x; A0[1] = (_Float16)xa.y;
    A0[2] = (_Float16)xa.z; A0[3] = (_Float16)xa.w;
    A0[4] = (_Float16)xb.x; A0[5] = (_Float16)xb.y;
    A0[6] = (_Float16)xb.z; A0[7] = (_Float16)xb.w;
    xa = *(const float4*)(p + 32);
    xb = *(const float4*)(p + 36);
    A1[0] = (_Float16)xa.x; A1[1] = (_Float16)xa.y;
    A1[2] = (_Float16)xa.z; A1[3] = (_Float16)xa.w;
    A1[4] = (_Float16)xb.x; A1[5] = (_Float16)xb.y;
    A1[6] = (_Float16)xb.z; A1[7] = (_Float16)xb.w;
  }

#pragma unroll
  for (int c = 0; c < 4; c++) {
    int o = c * 16 + r;
    {
      const f16x8* b0 = (const f16x8*)(Wl16 + (size_t)o * 64 + kg * 8);
      const f16x8* b1 = (const f16x8*)(Wl16 + (size_t)o * 64 + 32 + kg * 8);
      f32x4v acc;
      float bv = bl[o];
      acc[0] = bv; acc[1] = bv; acc[2] = bv; acc[3] = bv;
      acc = __builtin_amdgcn_mfma_f32_16x16x32_f16(A0, b0[0], acc, 0, 0, 0);
      acc = __builtin_amdgcn_mfma_f32_16x16x32_f16(A1, b1[0], acc, 0, 0, 0);
#pragma unroll
      for (int g = 0; g < 4; g++) {
        int nd = n0 + kg * 4 + g;
        if (nd < rows) xl[(size_t)nd * 64 + o] = (_Float16)acc[g];
      }
    }
    {
      const f16x8* b0 = (const f16x8*)(Wr16 + (size_t)o * 64 + kg * 8);
      const f16x8* b1 = (const f16x8*)(Wr16 + (size_t)o * 64 + 32 + kg * 8);
      f32x4v acc;
      float bv = br[o];
      acc[0] = bv; acc[1] = bv; acc[2] = bv; acc[3] = bv;
      acc = __builtin_amdgcn_mfma_f32_16x16x32_f16(A0, b0[0], acc, 0, 0, 0);
      acc = __builtin_amdgcn_mfma_f32_16x16x32_f16(A1, b1[0], acc, 0, 0, 0);
#pragma unroll
      for (int g = 0; g < 4; g++) {
        int nd = n0 + kg * 4 + g;
        if (nd < rows) xr[(size_t)nd * 64 + o] = (_Float16)acc[g];
      }
    }
  }
#endif
}

// ---------------------------------------------------------------------------
// Fused GATv2 layer (round-11 proven — best measured): one wave per
// (degree-sorted) node; 16/8/4-full + 4-padded chunks; scalar csr_src
// (readfirstlane -> SALU addressing); wave-uniform attr s_loads; fp16 xl
// gathers; ea via fdot2; LDS-free DPP reduction; online-max softmax via raw
// v_exp_f32 (exp2 domain). Epilogue = folded conv_bias+BN, exact GELU,
// residual.
// ---------------------------------------------------------------------------
template <bool CONTIG>
__global__ __launch_bounds__(256) void gat_fused_kernel(
    const int* __restrict__ perm, const int* __restrict__ csr_src,
    const int* __restrict__ csr_eid, const int* __restrict__ row_ptr,
    const unsigned* __restrict__ attr_u, const float* __restrict__ edge_attr,
    const _Float16* __restrict__ xl, const _Float16* __restrict__ xr,
    const float* __restrict__ We, const float* __restrict__ att,
    const float* __restrict__ conv_bias, const float* __restrict__ gamma,
    const float* __restrict__ beta, const float* __restrict__ mean,
    const float* __restrict__ var, float* __restrict__ h, int N_) {
  int widx = (blockIdx.x * 256 + threadIdx.x) >> 6;
  if (widx >= N_) return;
  int d = __builtin_amdgcn_readfirstlane(perm[widx]);
  int j = threadIdx.x & 63;
  half2v Wek2[8];
  float Wekf[16];
  if constexpr (CONTIG) {
#pragma unroll
    for (int q = 0; q < 8; q++) {
      Wek2[q][0] = (_Float16)We[j * 16 + 2 * q];
      Wek2[q][1] = (_Float16)We[j * 16 + 2 * q + 1];
    }
  } else {
#pragma unroll
    for (int k = 0; k < 16; k++) Wekf[k] = We[j * 16 + k];
  }
  float att_j = att[j] * ATT_SCALE;
  float sc = rsqrtf(var[j] + BN_EPS) * gamma[j];
  float sh = (conv_bias[j] - mean[j]) * sc + beta[j];

  int beg = __builtin_amdgcn_readfirstlane(row_ptr[d]);
  int end = __builtin_amdgcn_readfirstlane(row_ptr[d + 1]);
  float xrj = (float)xr[(size_t)d * 64 + j];
  float m = -INFINITY, l = 0.f, acc = 0.f;

  auto chunk = [&](int base, auto C_, auto PAD_) {
    constexpr int C = decltype(C_)::v;
    constexpr bool PAD = decltype(PAD_)::v;
    int si[C];
#pragma unroll
    for (int t = 0; t < C; t++) {
      int idx = PAD ? min(base + t, end - 1) : (base + t);
      si[t] = __builtin_amdgcn_readfirstlane(csr_src[idx]);  // SGPR -> SALU addr
    }
    float xlv[C];
#pragma unroll
    for (int t = 0; t < C; t++)
      xlv[t] = (float)xl[(size_t)si[t] * 64 + j];
    float v[C];
#pragma unroll
    for (int t = 0; t < C; t++) {
      int idx = PAD ? min(base + t, end - 1) : (base + t);
      float ea;
      if constexpr (CONTIG) {
        const uint4* ap = (const uint4*)(attr_u + (size_t)idx * 8);
        uint4 ua = ap[0], ub = ap[1];  // uniform -> s_load_dwordx4
        ea = 0.f;
        ea = FDOT2(u2h(ua.x), Wek2[0], ea);
        ea = FDOT2(u2h(ua.y), Wek2[1], ea);
        ea = FDOT2(u2h(ua.z), Wek2[2], ea);
        ea = FDOT2(u2h(ua.w), Wek2[3], ea);
        ea = FDOT2(u2h(ub.x), Wek2[4], ea);
        ea = FDOT2(u2h(ub.y), Wek2[5], ea);
        ea = FDOT2(u2h(ub.z), Wek2[6], ea);
        ea = FDOT2(u2h(ub.w), Wek2[7], ea);
      } else {
        const float4* ap =
            (const float4*)(edge_attr + (size_t)csr_eid[idx] * 16);
        float4 a0 = ap[0], a1 = ap[1], a2 = ap[2], a3 = ap[3];
        ea = a0.x * Wekf[0]  + a0.y * Wekf[1]  + a0.z * Wekf[2]  + a0.w * Wekf[3]
           + a1.x * Wekf[4]  + a1.y * Wekf[5]  + a1.z * Wekf[6]  + a1.w * Wekf[7]
           + a2.x * Wekf[8]  + a2.y * Wekf[9]  + a2.z * Wekf[10] + a2.w * Wekf[11]
           + a3.x * Wekf[12] + a3.y * Wekf[13] + a3.z * Wekf[14] + a3.w * Wekf[15];
      }
      float z = xlv[t] + xrj + ea;
      z = fmaxf(z, NEG_SLOPE * z);  // leaky_relu
      float p = wave_sum64(z * att_j);
      v[t] = (!PAD || (base + t < end)) ? p : -INFINITY;
    }
    float mc = v[0];
#pragma unroll
    for (int t = 1; t < C; t++) mc = fmaxf(mc, v[t]);
    float newm = fmaxf(m, mc);
    float s = FEXP(m - newm);  // first chunk: exp(-inf)=0
    l *= s;
    acc *= s;
#pragma unroll
    for (int t = 0; t < C; t++) {
      float w = FEXP(v[t] - newm);  // masked slots: exp(-inf)=0
      l += w;
      acc += w * xlv[t];
    }
    m = newm;
  };

  int base = beg;
  for (; base + 16 <= end; base += 16) chunk(base, IC<16>{}, BC<false>{});
  if (base + 8 <= end) {
    chunk(base, IC<8>{}, BC<false>{});
    base += 8;
  }
  if (base + 4 <= end) {
    chunk(base, IC<4>{}, BC<false>{});
    base += 4;
  }
  if (base < end) chunk(base, IC<4>{}, BC<true>{});

  float val = acc / (l + 1e-16f) * sc + sh;  // conv_bias+BN folded
  float g = 0.5f * val * (1.f + erff(val * 0.70710678118654752f));
  h[(size_t)d * 64 + j] += g;
}

// ---------------------------------------------------------------------------
// Final: out128 = h @ lin_W.T + lin_b, pooled per graph (round-4 proven).
// ---------------------------------------------------------------------------
__global__ __launch_bounds__(256, 2) void lin_pool_kernel(
    const float* __restrict__ h, const float* __restrict__ lin_W,
    const float* __restrict__ lin_b, const int* __restrict__ batch,
    const float* __restrict__ counts, float* __restrict__ pooled, int rows) {
  __shared__ float shh[4096];
  int lane = threadIdx.x & 63;
  int w = threadIdx.x >> 6;
  int n0 = blockIdx.x * 64;

  {
    int gmax = rows * 64 - 4;
#pragma unroll
    for (int i = 0; i < 4; i++) {
      int off = w * 1024 + i * 256 + lane * 4;
      int g = min(n0 * 64 + off, gmax);
      *(float4*)(shh + off) = *(const float4*)(h + g);
    }
  }

  float4 W0[16], W1[16];
#pragma unroll
  for (int q = 0; q < 16; q++) W0[q] = ((const float4*)(lin_W + lane * 64))[q];
#pragma unroll
  for (int q = 0; q < 16; q++)
    W1[q] = ((const float4*)(lin_W + (lane + 64) * 64))[q];
  float b0 = lin_b[lane], b1 = lin_b[lane + 64];

  int curg = -1;
  float acc0 = 0.f, acc1 = 0.f;
  int lim = min(16, rows - n0 - w * 16);
#pragma unroll 1
  for (int t = 0; t < lim; t++) {
    int r = w * 16 + t;
    __builtin_amdgcn_sched_barrier(0);
    float d0 = b0, d1 = b1;
#pragma unroll
    for (int q = 0; q < 16; q++) {
      float4 v = *(const float4*)(shh + r * 64 + q * 4);
      FMA4(d0, v, W0[q]);
      FMA4(d1, v, W1[q]);
    }
    int g = batch[n0 + r];
    if (g != curg) {
      if (curg >= 0) {
        float inv = 1.f / fmaxf(counts[curg], 1.f);
        atomicAdd(&pooled[curg * 128 + lane], acc0 * inv);
        atomicAdd(&pooled[curg * 128 + 64 + lane], acc1 * inv);
      }
      curg = g;
      acc0 = 0.f;
      acc1 = 0.f;
    }
    acc0 += d0;
    acc1 += d1;
  }
  if (curg >= 0) {
    float inv = 1.f / fmaxf(counts[curg], 1.f);
    atomicAdd(&pooled[curg * 128 + lane], acc0 * inv);
    atomicAdd(&pooled[curg * 128 + 64 + lane], acc1 * inv);
  }
}

extern "C" void kernel_launch(void* const* d_in, const int* in_sizes, int n_in,
                              void* d_out, int out_size, void* d_ws, size_t ws_size,
                              hipStream_t stream) {
  const float* x         = (const float*)d_in[0];
  const int*   edge_index= (const int*)  d_in[1];
  const float* edge_attr = (const float*)d_in[2];
  const int*   batch     = (const int*)  d_in[3];
  const float* emb_W     = (const float*)d_in[4];
  const float* emb_b     = (const float*)d_in[5];
  const float* Wl        = (const float*)d_in[6];
  const float* bl        = (const float*)d_in[7];
  const float* Wr        = (const float*)d_in[8];
  const float* br        = (const float*)d_in[9];
  const float* We        = (const float*)d_in[10];
  const float* att       = (const float*)d_in[11];
  const float* conv_bias = (const float*)d_in[12];
  const float* bn_gamma  = (const float*)d_in[13];
  const float* bn_beta   = (const float*)d_in[14];
  const float* bn_mean   = (const float*)d_in[15];
  const float* bn_var    = (const float*)d_in[16];
  const float* lin_W     = (const float*)d_in[17];
  const float* lin_b     = (const float*)d_in[18];

  const int N_ = in_sizes[0] / 64;
  const int E_ = in_sizes[1] / 2;
  const int G_ = out_size / 128;
  const int* src = edge_index;
  const int* dst = edge_index + E_;

  const int Npad = (N_ + 3) & ~3;
  const int Epad = (E_ + 19) & ~3;
  const int nseg = (N_ + 255) / 256;

  // Workspace layout (floats). xl/xr fp16. w16 = fp16 Wl(3)+Wr(3) packed.
  float* ws      = (float*)d_ws;
  float* h       = ws;                                 // N*64
  _Float16* xl   = (_Float16*)(h + (size_t)N_ * 64);   // N*64 halfs
  _Float16* xr   = xl + (size_t)N_ * 64;               // N*64 halfs
  int*   csr_src = (int*)(xr + (size_t)N_ * 64);       // Epad
  int*   csr_eid = csr_src + Epad;                     // Epad
  int*   row_ptr = csr_eid + Epad;                     // Npad+4
  int*   cursor  = row_ptr + (Npad + 4);               // Npad
  int*   deg     = cursor + Npad;                      // Npad
  float* counts  = (float*)(deg + Npad);               // G
  int*   segTot  = (int*)(counts + G_);                // nseg+8
  int*   bins    = segTot + nseg + 8;                  // 128
  int*   perm    = bins + 128;                         // Npad
  uintptr_t abp  = (uintptr_t)(perm + Npad);
  abp = (abp + 15) & ~(uintptr_t)15;
  _Float16* w16  = (_Float16*)abp;                     // 24576 halfs (48KB)
  uintptr_t abp2 = abp + 24576 * sizeof(_Float16);
  unsigned* attr_u = (unsigned*)abp2;                  // E*8 uints (optional)

  size_t base_bytes = (abp2 - (uintptr_t)d_ws);
  bool contig = ws_size >= base_bytes + (size_t)E_ * 32 + 64;

  const int hgrid = (max(E_, N_) + 255) / 256;
  const int ngrid = (N_ + 255) / 256;
  const int egrid = (E_ + 255) / 256;

  // --- CSR build + counts + degree-sort + weight pack (fused chain) ---
  hipMemsetAsync(deg, 0, ((size_t)Npad + G_ + nseg + 8 + 128) * 4, stream);
  hist_kernel<<<hgrid, 256, 0, stream>>>(dst, batch, deg, counts, Wl, Wr,
                                         w16, E_, N_);
  scanA_kernel<<<min(nseg, 1024), 256, 0, stream>>>(deg, row_ptr, segTot,
                                                    bins, N_, nseg);
  scanB_kernel<<<1, 256, 0, stream>>>(segTot, bins, nseg);
  scanC_kernel<<<ngrid, 256, 0, stream>>>(row_ptr, segTot, cursor, deg, bins,
                                          perm, csr_src, csr_eid, N_, E_);
  scatter_kernel<<<egrid, 256, 0, stream>>>(src, dst, cursor, csr_src,
                                            csr_eid, E_);
  if (contig) {
    permute_attr_kernel<<<egrid, 256, 0, stream>>>(
        (const float4*)edge_attr, csr_eid, attr_u, E_);
  }

  // emb (fp32-exact) + fused layer-0 xl/xr (MFMA from LDS slab)
  const int tgrid = (N_ + 63) / 64;
  emb_kernel<<<tgrid, 256, 0, stream>>>(x, emb_W, emb_b, w16, bl,
                                        w16 + 12288, br, h, xl, xr, N_);

  const int gatBlocks = (N_ + 3) / 4;  // one wave per node
  for (int l = 0; l < 3; l++) {
    if (l > 0) {
      linx_mfma_kernel<<<tgrid, 256, 0, stream>>>(
          h, w16 + (size_t)l * 4096, bl + l * 64,
          w16 + 12288 + (size_t)l * 4096, br + l * 64, xl, xr, N_);
    }
    if (contig) {
      gat_fused_kernel<true><<<gatBlocks, 256, 0, stream>>>(
          perm, csr_src, csr_eid, row_ptr, attr_u, edge_attr, xl, xr,
          We + (size_t)l * 1024, att + l * 64, conv_bias + l * 64,
          bn_gamma + l * 64, bn_beta + l * 64, bn_mean + l * 64,
          bn_var + l * 64, h, N_);
    } else {
      gat_fused_kernel<false><<<gatBlocks, 256, 0, stream>>>(
          perm, csr_src, csr_eid, row_ptr, attr_u, edge_attr, xl, xr,
          We + (size_t)l * 1024, att + l * 64, conv_bias + l * 64,
          bn_gamma + l * 64, bn_beta + l * 64, bn_mean + l * 64,
          bn_var + l * 64, h, N_);
    }
  }

  hipMemsetAsync(d_out, 0, (size_t)G_ * 128 * 4, stream);
  lin_pool_kernel<<<(N_ + 63) / 64, 256, 0, stream>>>(
      h, lin_W, lin_b, batch, counts, (float*)d_out, N_);
}